// Round 1
// baseline (641.163 us; speedup 1.0000x reference)
//
#include <hip/hip_runtime.h>
#include <hip/hip_bf16.h>

#define N_NODES 8192
#define DD 256
#define MAXD 128

typedef __attribute__((ext_vector_type(8))) __bf16 bf16x8;
typedef __attribute__((ext_vector_type(4))) float floatx4;

__device__ __forceinline__ void async16(void* lds, const void* g) {
  __builtin_amdgcn_global_load_lds((const __attribute__((address_space(1))) void*)g,
                                   (__attribute__((address_space(3))) void*)lds, 16, 0, 0);
}

// ---------------- weight transpose+convert: W [K][N] f32 -> Wt [N][K] bf16 ----------------
__global__ __launch_bounds__(256) void transpose_bf16(const float* __restrict__ in,
                                                      __hip_bfloat16* __restrict__ out,
                                                      int K, int N) {
  __shared__ float tile[32][33];
  const int x = threadIdx.x, y = threadIdx.y;
  const size_t base = (size_t)blockIdx.z * K * N;
  const int k0 = blockIdx.x * 32, n0 = blockIdx.y * 32;
#pragma unroll
  for (int r = 0; r < 4; ++r)
    tile[y + r * 8][x] = in[base + (size_t)(k0 + y + r * 8) * N + n0 + x];
  __syncthreads();
#pragma unroll
  for (int r = 0; r < 4; ++r)
    out[base + (size_t)(n0 + y + r * 8) * K + k0 + x] = __float2bfloat16(tile[x][y + r * 8]);
}

// ---------------- CSR build from dense binary adjacency ----------------
__global__ __launch_bounds__(256) void csr_build(const float* __restrict__ graph,
                                                 int* __restrict__ col_idx,
                                                 int* __restrict__ deg) {
  __shared__ int cnt;
  const int i = blockIdx.x;
  const int t = threadIdx.x;
  if (t == 0) cnt = 0;
  __syncthreads();
  const float4* row = (const float4*)(graph + (size_t)i * N_NODES);
#pragma unroll
  for (int it = 0; it < 8; ++it) {
    const int idx = it * 256 + t;
    float4 v = row[idx];
    if (v.x > 0.f) { int p = atomicAdd(&cnt, 1); if (p < MAXD) col_idx[(size_t)i * MAXD + p] = idx * 4 + 0; }
    if (v.y > 0.f) { int p = atomicAdd(&cnt, 1); if (p < MAXD) col_idx[(size_t)i * MAXD + p] = idx * 4 + 1; }
    if (v.z > 0.f) { int p = atomicAdd(&cnt, 1); if (p < MAXD) col_idx[(size_t)i * MAXD + p] = idx * 4 + 2; }
    if (v.w > 0.f) { int p = atomicAdd(&cnt, 1); if (p < MAXD) col_idx[(size_t)i * MAXD + p] = idx * 4 + 3; }
  }
  __syncthreads();
  if (t == 0) deg[i] = cnt < MAXD ? cnt : MAXD;
}

// ---------------- adaptive-field mask MLP: D->54->1, sigmoid*3, gaussian mask ----------------
__global__ __launch_bounds__(256) void mask_mlp(const float* __restrict__ x,
                                                const float* __restrict__ W1,
                                                const float* __restrict__ b1,
                                                const float* __restrict__ W2,
                                                const float* __restrict__ b2,
                                                float* __restrict__ maskL) {
  __shared__ float hs[4][256];
  const int w = threadIdx.x >> 6, lane = threadIdx.x & 63;
  const int n = blockIdx.x * 4 + w;
  float4 v = ((const float4*)(x + (size_t)n * 256))[lane];
  hs[w][lane * 4 + 0] = v.x; hs[w][lane * 4 + 1] = v.y;
  hs[w][lane * 4 + 2] = v.z; hs[w][lane * 4 + 3] = v.w;
  __syncthreads();
  const int j = lane;
  float c = 0.f;
  if (j < 54) {
    float hj = b1[j];
    for (int k = 0; k < 256; k += 4) {
      float4 hv = *(const float4*)&hs[w][k];
      hj += hv.x * W1[(k + 0) * 54 + j];
      hj += hv.y * W1[(k + 1) * 54 + j];
      hj += hv.z * W1[(k + 2) * 54 + j];
      hj += hv.w * W1[(k + 3) * 54 + j];
    }
    c = fmaxf(hj, 0.f) * W2[j];
  }
#pragma unroll
  for (int off = 32; off; off >>= 1) c += __shfl_xor(c, off);
  float z = c + b2[0];
  float thr = 3.f / (1.f + expf(-z));
  if (lane < 3) {
    float d = (float)lane - thr;
    maskL[lane * N_NODES + n] = expf(-d * d);
  }
}

// ---------------- attention score MLP: e[n] = relu(h@W1+b1)@W2 + b2 ----------------
__global__ __launch_bounds__(256) void att_e(const float* __restrict__ h,
                                             const float* __restrict__ W1,
                                             const float* __restrict__ b1,
                                             const float* __restrict__ W2,
                                             const float* __restrict__ b2,
                                             float* __restrict__ e) {
  __shared__ float hs[4][256];
  const int w = threadIdx.x >> 6, lane = threadIdx.x & 63;
  const int n = blockIdx.x * 4 + w;
  float4 v = ((const float4*)(h + (size_t)n * 256))[lane];
  hs[w][lane * 4 + 0] = v.x; hs[w][lane * 4 + 1] = v.y;
  hs[w][lane * 4 + 2] = v.z; hs[w][lane * 4 + 3] = v.w;
  __syncthreads();
  const int j = lane;
  float hj = b1[j];
  for (int k = 0; k < 256; k += 4) {
    float4 hv = *(const float4*)&hs[w][k];
    hj += hv.x * W1[(k + 0) * 64 + j];
    hj += hv.y * W1[(k + 1) * 64 + j];
    hj += hv.z * W1[(k + 2) * 64 + j];
    hj += hv.w * W1[(k + 3) * 64 + j];
  }
  float c = fmaxf(hj, 0.f) * W2[j];
#pragma unroll
  for (int off = 32; off; off >>= 1) c += __shfl_xor(c, off);
  if (lane == 0) e[n] = c + b2[0];
}

// ---------------- sparse softmax-attention aggregation: h_agg = deg * (softmax(att) @ h) ----------------
__global__ __launch_bounds__(256) void agg_kernel(const float* __restrict__ hcur,
                                                  const float* __restrict__ e,
                                                  const int* __restrict__ col_idx,
                                                  const int* __restrict__ deg,
                                                  __hip_bfloat16* __restrict__ hagg) {
  const int i = blockIdx.x;
  const int t = threadIdx.x;
  __shared__ int cols[MAXD];
  __shared__ float ev[MAXD];
  __shared__ float wts[MAXD];
  __shared__ float red[2];
  const int d = deg[i];
  if (t < d) { int c = col_idx[(size_t)i * MAXD + t]; cols[t] = c; ev[t] = e[c]; }
  __syncthreads();
  if (t < 64) {
    float m = -3.0e38f;
    if (t < d) m = ev[t];
    if (t + 64 < d) m = fmaxf(m, ev[t + 64]);
#pragma unroll
    for (int off = 32; off; off >>= 1) m = fmaxf(m, __shfl_xor(m, off));
    float s = 0.f;
    if (t < d) s = expf(ev[t] - m);
    if (t + 64 < d) s += expf(ev[t + 64] - m);
#pragma unroll
    for (int off = 32; off; off >>= 1) s += __shfl_xor(s, off);
    if (t == 0) { red[0] = m; red[1] = s; }
  }
  __syncthreads();
  const float mx = red[0];
  const float scale = (float)d / red[1];
  if (t < d) wts[t] = expf(ev[t] - mx) * scale;
  __syncthreads();
  float acc = 0.f;
  for (int j = 0; j < d; ++j) acc += wts[j] * hcur[(size_t)cols[j] * 256 + t];
  hagg[(size_t)i * 256 + t] = __float2bfloat16(acc);
}

// ---------------- bf16 MFMA GEMM: C[M,N] = A[M,K](bf16) @ Wt[N,K]^T (bf16) + bias ----------------
template <bool OUT_BF16, bool RELU>
__global__ __launch_bounds__(256) void gemm_bf16(const __hip_bfloat16* __restrict__ A,
                                                 const __hip_bfloat16* __restrict__ Wt,
                                                 const float* __restrict__ bias,
                                                 void* __restrict__ Cout, int K, int ldc) {
  __shared__ __align__(16) char As[8192];  // 64 rows x 64 k, 16B chunks, XOR-swizzled slots
  __shared__ __align__(16) char Ws[8192];
  const int tid = threadIdx.x;
  const int w = tid >> 6;
  const int lane = tid & 63;
  const int m0 = blockIdx.x * 64;
  const int n0 = blockIdx.y * 64;
  const int q = lane >> 4, l15 = lane & 15;
  floatx4 acc[4] = {};

  const int nKT = K >> 6;
  for (int kt = 0; kt < nKT; ++kt) {
    const int kbase = kt * 64;
#pragma unroll
    for (int r = 0; r < 2; ++r) {
      const int s = w * 128 + r * 64 + lane;     // slot index
      const int m = s >> 3;
      const int g = (s & 7) ^ (m & 7);           // un-swizzle to source chunk
      async16(As + (size_t)(w * 128 + r * 64) * 16,
              (const void*)(A + (size_t)(m0 + m) * K + kbase + g * 8));
      async16(Ws + (size_t)(w * 128 + r * 64) * 16,
              (const void*)(Wt + (size_t)(n0 + m) * K + kbase + g * 8));
    }
    __syncthreads();
#pragma unroll
    for (int kk = 0; kk < 2; ++kk) {
      const int gq = kk * 4 + q;
      const int nsl = w * 16 + l15;
      bf16x8 b = *(const bf16x8*)(Ws + (size_t)(nsl * 8 + (gq ^ (nsl & 7))) * 16);
#pragma unroll
      for (int mt = 0; mt < 4; ++mt) {
        const int msl = mt * 16 + l15;
        bf16x8 a = *(const bf16x8*)(As + (size_t)(msl * 8 + (gq ^ (msl & 7))) * 16);
        acc[mt] = __builtin_amdgcn_mfma_f32_16x16x32_bf16(a, b, acc[mt], 0, 0, 0);
      }
    }
    __syncthreads();
  }
  const int n = n0 + w * 16 + l15;
  const float bv = bias[n - n0 + (n0)];  // == bias[n]
#pragma unroll
  for (int mt = 0; mt < 4; ++mt) {
#pragma unroll
    for (int r2 = 0; r2 < 4; ++r2) {
      const int m = m0 + mt * 16 + q * 4 + r2;
      float v = acc[mt][r2] + bv;
      if (RELU) v = fmaxf(v, 0.f);
      if (OUT_BF16)
        ((__hip_bfloat16*)Cout)[(size_t)m * ldc + n] = __float2bfloat16(v);
      else
        ((float*)Cout)[(size_t)m * ldc + n] = v;
    }
  }
}

// ---------------- BatchNorm stats (column sums / sumsq via atomics) ----------------
__global__ __launch_bounds__(256) void bn_stats(const float* __restrict__ h2,
                                                float* __restrict__ stats) {
  const int c = threadIdx.x;
  const int r0 = blockIdx.x * 64;
  float s = 0.f, s2 = 0.f;
  for (int r = 0; r < 64; ++r) {
    float v = h2[(size_t)(r0 + r) * 256 + c];
    s += v; s2 += v * v;
  }
  atomicAdd(&stats[c], s);
  atomicAdd(&stats[256 + c], s2);
}

// ---------------- BN apply + ReLU + next-h + masked rep into feat(bf16) ----------------
__global__ __launch_bounds__(256) void bn_apply(const float* __restrict__ h2,
                                                const float* __restrict__ stats,
                                                const float* __restrict__ gamma,
                                                const float* __restrict__ beta,
                                                const float* __restrict__ maskl,
                                                float* __restrict__ hout,
                                                __hip_bfloat16* __restrict__ feat, int l) {
  const int c = threadIdx.x;
  const size_t n = blockIdx.x;
  const float mean = stats[c] * (1.f / 8192.f);
  const float var = stats[256 + c] * (1.f / 8192.f) - mean * mean;
  const float inv = rsqrtf(var + 1e-5f);
  float v = (h2[n * 256 + c] - mean) * inv * gamma[c] + beta[c];
  v = fmaxf(v, 0.f);
  hout[n * 256 + c] = v;
  feat[n * 768 + l * 256 + c] = __float2bfloat16(v * maskl[n]);
}

extern "C" void kernel_launch(void* const* d_in, const int* in_sizes, int n_in,
                              void* d_out, int out_size, void* d_ws, size_t ws_size,
                              hipStream_t stream) {
  (void)in_sizes; (void)n_in; (void)out_size; (void)ws_size;
  const float* graph   = (const float*)d_in[0];
  const float* x       = (const float*)d_in[1];
  const float* att_W1  = (const float*)d_in[2];
  const float* att_b1  = (const float*)d_in[3];
  const float* att_W2  = (const float*)d_in[4];
  const float* att_b2  = (const float*)d_in[5];
  const float* mlp_W1  = (const float*)d_in[6];
  const float* mlp_b1  = (const float*)d_in[7];
  const float* mlp_W2  = (const float*)d_in[8];
  const float* mlp_b2  = (const float*)d_in[9];
  const float* bn_g    = (const float*)d_in[10];
  const float* bn_b    = (const float*)d_in[11];
  const float* mask_W1 = (const float*)d_in[12];
  const float* mask_b1 = (const float*)d_in[13];
  const float* mask_W2 = (const float*)d_in[14];
  const float* mask_b2 = (const float*)d_in[15];
  const float* pred_W  = (const float*)d_in[16];
  const float* pred_b  = (const float*)d_in[17];
  float* out = (float*)d_out;

  char* ws = (char*)d_ws;
  size_t off = 0;
  auto carve = [&](size_t bytes) -> char* {
    char* p = ws + off;
    off += (bytes + 255) & ~(size_t)255;
    return p;
  };
  __hip_bfloat16* Wt1    = (__hip_bfloat16*)carve((size_t)3 * 256 * 256 * 2);
  __hip_bfloat16* Wt2    = (__hip_bfloat16*)carve((size_t)3 * 256 * 256 * 2);
  __hip_bfloat16* predWt = (__hip_bfloat16*)carve((size_t)64 * 768 * 2);
  int*   col_idx = (int*)carve((size_t)N_NODES * MAXD * 4);
  int*   deg     = (int*)carve((size_t)N_NODES * 4);
  float* evec    = (float*)carve((size_t)N_NODES * 4);
  float* maskL   = (float*)carve((size_t)3 * N_NODES * 4);
  float* stats   = (float*)carve((size_t)3 * 512 * 4);
  float* h_buf   = (float*)carve((size_t)N_NODES * DD * 4);
  float* h2      = (float*)carve((size_t)N_NODES * DD * 4);
  __hip_bfloat16* hagg = (__hip_bfloat16*)carve((size_t)N_NODES * DD * 2);
  __hip_bfloat16* H1   = (__hip_bfloat16*)carve((size_t)N_NODES * DD * 2);
  __hip_bfloat16* feat = (__hip_bfloat16*)carve((size_t)N_NODES * 768 * 2);

  hipMemsetAsync(stats, 0, 3 * 512 * 4, stream);
  transpose_bf16<<<dim3(8, 8, 3), dim3(32, 8), 0, stream>>>(mlp_W1, Wt1, 256, 256);
  transpose_bf16<<<dim3(8, 8, 3), dim3(32, 8), 0, stream>>>(mlp_W2, Wt2, 256, 256);
  transpose_bf16<<<dim3(24, 2, 1), dim3(32, 8), 0, stream>>>(pred_W, predWt, 768, 64);
  csr_build<<<N_NODES, 256, 0, stream>>>(graph, col_idx, deg);
  mask_mlp<<<N_NODES / 4, 256, 0, stream>>>(x, mask_W1, mask_b1, mask_W2, mask_b2, maskL);

  const float* hcur = x;
  for (int l = 0; l < 3; ++l) {
    att_e<<<N_NODES / 4, 256, 0, stream>>>(hcur, att_W1 + (size_t)l * 256 * 64, att_b1 + l * 64,
                                           att_W2 + l * 64, att_b2 + l, evec);
    agg_kernel<<<N_NODES, 256, 0, stream>>>(hcur, evec, col_idx, deg, hagg);
    gemm_bf16<true, true><<<dim3(128, 4), 256, 0, stream>>>(
        hagg, Wt1 + (size_t)l * 65536, mlp_b1 + l * 256, H1, 256, 256);
    gemm_bf16<false, false><<<dim3(128, 4), 256, 0, stream>>>(
        H1, Wt2 + (size_t)l * 65536, mlp_b2 + l * 256, h2, 256, 256);
    bn_stats<<<128, 256, 0, stream>>>(h2, stats + l * 512);
    bn_apply<<<N_NODES, 256, 0, stream>>>(h2, stats + l * 512, bn_g + l * 256, bn_b + l * 256,
                                          maskL + l * N_NODES, h_buf, feat, l);
    hcur = h_buf;
  }
  gemm_bf16<false, false><<<dim3(128, 1), 256, 0, stream>>>(feat, predWt, pred_b, out, 768, 64);
}